// Round 6
// baseline (370.664 us; speedup 1.0000x reference)
//
#include <hip/hip_runtime.h>
#include <math.h>

#define AS1 __attribute__((address_space(1)))
#define AS3 __attribute__((address_space(3)))

typedef _Float16 f16x8 __attribute__((ext_vector_type(8)));
typedef float f32x4 __attribute__((ext_vector_type(4)));

#define NROWS 8192
#define DDIM  512

// ---------------------------------------------------------------------------
// Kernel 1: per-row prep. One wave (64 lanes) per row; each lane owns 8 cols.
// ---------------------------------------------------------------------------
__global__ __launch_bounds__(256) void prep_kernel(
    const float* __restrict__ x,
    const float* __restrict__ muk,
    const float* __restrict__ rho,
    const float* __restrict__ vark,
    const float* __restrict__ mu_bias,
    const float* __restrict__ var_bias,
    float* __restrict__ mu_out,
    _Float16* __restrict__ xh,
    _Float16* __restrict__ ah,
    float* __restrict__ dvec)
{
    const int wave = threadIdx.x >> 6;
    const int lane = threadIdx.x & 63;
    const int row  = blockIdx.x * 4 + wave;
    const int k    = lane * 8;

    const float4 x0 = *(const float4*)(x + (size_t)row * DDIM + k);
    const float4 x1 = *(const float4*)(x + (size_t)row * DDIM + k + 4);
    const float4 m0 = *(const float4*)(muk + k);
    const float4 m1 = *(const float4*)(muk + k + 4);
    const float4 r0 = *(const float4*)(rho + k);
    const float4 r1 = *(const float4*)(rho + k + 4);
    const float4 v0 = *(const float4*)(vark + k);
    const float4 v1 = *(const float4*)(vark + k + 4);

    float xv[8] = {x0.x, x0.y, x0.z, x0.w, x1.x, x1.y, x1.z, x1.w};
    float rv[8] = {r0.x, r0.y, r0.z, r0.w, r1.x, r1.y, r1.z, r1.w};
    float mv[8] = {m0.x, m0.y, m0.z, m0.w, m1.x, m1.y, m1.z, m1.w};
    float vv[8] = {v0.x, v0.y, v0.z, v0.w, v1.x, v1.y, v1.z, v1.w};

    f16x8 hx, ha;
    float dm = 0.f, dv = 0.f;
#pragma unroll
    for (int j = 0; j < 8; ++j) {
        hx[j] = (_Float16)xv[j];
        ha[j] = (_Float16)(xv[j] * rv[j]);
        dm += xv[j] * mv[j];
        dv += xv[j] * vv[j];
    }
    *(f16x8*)(xh + (size_t)row * DDIM + k) = hx;
    *(f16x8*)(ah + (size_t)row * DDIM + k) = ha;

#pragma unroll
    for (int off = 32; off > 0; off >>= 1) {
        dm += __shfl_down(dm, off, 64);
        dv += __shfl_down(dv, off, 64);
    }
    if (lane == 0) {
        mu_out[row] = dm + mu_bias[0];
        float z  = dv + var_bias[0];
        float sp = fmaxf(z, 0.f) + log1pf(expf(-fabsf(z)));  // stable softplus
        dvec[row] = sp + 1e-8f;
    }
}

// ---------------------------------------------------------------------------
// Kernel 2 — DIAGNOSTIC BUILD (round 6).
// Identical to v4 (cell-major + NT stores + counted-vmcnt pipeline) EXCEPT:
// the 16-tile K-pipeline runs TWICE (REP=2), accumulating 2x the true sum;
// the epilogue multiplies by exactly 0.5f (power of two -> bit-exact).
// Purpose: push cov to top-1 in the rocprof table to finally read its
// counters (MfmaUtil / FETCH / WRITE / occupancy), and split T_kloop vs
// T_epilogue via:  T_k + T_epi ~= 155us (known),  2*T_k + T_epi = measured.
// The 0.5f-fold keeps rep-0's MFMAs live (no DCE, rule 17) and correctness
// exact. One extra __syncthreads per rep guards LDS slot reuse.
// ---------------------------------------------------------------------------
__device__ __forceinline__ void gload_lds16(const void* g, void* l)
{
    __builtin_amdgcn_global_load_lds((AS1 void*)g, (AS3 void*)l, 16, 0, 0);
}

__global__ __launch_bounds__(256) void cov_kernel(
    const _Float16* __restrict__ A,   // ah: 8192 x 512 (rows of x*rho)
    const _Float16* __restrict__ B,   // xh: 8192 x 512 (rows of x)
    const float* __restrict__ dvec,
    const float* __restrict__ cov_bias,
    float* __restrict__ C)
{
    __shared__ _Float16 As[3][128 * 32];   // 3 x 8 KB
    __shared__ _Float16 Bs[3][128 * 32];

    const int t    = threadIdx.x;
    const int lane = t & 63;
    const int wave = t >> 6;
    const int wr   = wave >> 1;         // 0..1 : 64-row half
    const int wc   = wave & 1;          // 0..1 : 64-col half
    const int quad = lane >> 4;         // 0..3
    const int l16  = lane & 15;
    const int xc   = quad ^ ((l16 >> 1) & 3);   // swizzled read chunk

    // XCD-aware chunked swizzle over cell-major order.
    const int bid = blockIdx.x;
    const int tt  = (bid & 7) * 260 + (bid >> 3);

    // cell-major decode: cells are 8x8 blocks; blocks before cell-row SI:
    // base(SI) = 32*SI^2 + 4*SI
    int SI = (int)((sqrtf(1.f + 8.f * (float)tt) - 1.f) * 0.0625f);
    while (32 * (SI + 1) * (SI + 1) + 4 * (SI + 1) <= tt) ++SI;
    while (32 * SI * SI + 4 * SI > tt) --SI;
    const int rem = tt - (32 * SI * SI + 4 * SI);
    int SJ, ii, jj;
    if (rem < 64 * SI) {                 // full off-diagonal cell
        SJ = rem >> 6;
        const int w = rem & 63;
        ii = w >> 3;
        jj = w & 7;
    } else {                             // diagonal cell: 36 blocks, jj<=ii
        const int w = rem - 64 * SI;
        SJ = SI;
        ii = (int)((sqrtf(8.f * (float)w + 1.f) - 1.f) * 0.5f);
        while ((ii + 1) * (ii + 2) / 2 <= w) ++ii;
        while (ii * (ii + 1) / 2 > w) --ii;
        jj = w - ii * (ii + 1) / 2;
    }
    const int bi = SI * 8 + ii;
    const int bj = SJ * 8 + jj;

    const int rowBase = bi * 128;
    const int colBase = bj * 128;
    const float cb = cov_bias[0];

    f32x4 acc[4][4] = {};

    // staging: thread t owns LDS slot (row r = t>>2, chunk c = t&3, 16 B).
    // Pre-swizzled global source chunk g = c ^ ((r>>1)&3)  (rule 21).
    const int sr = t >> 2;
    const int sg = (t & 3) ^ ((sr >> 1) & 3);
    const _Float16* ga = A + ((size_t)(rowBase + sr)) * DDIM + sg * 8;
    const _Float16* gb = B + ((size_t)(colBase + sr)) * DDIM + sg * 8;

#define STAGE(kt, s) do {                                            \
        const int _k0 = (kt) * 32;                                   \
        gload_lds16(ga + _k0,             As[s] + t * 8);            \
        gload_lds16(ga + 64 * DDIM + _k0, As[s] + 2048 + t * 8);     \
        gload_lds16(gb + _k0,             Bs[s] + t * 8);            \
        gload_lds16(gb + 64 * DDIM + _k0, Bs[s] + 2048 + t * 8);     \
    } while (0)

    f16x8 af[4], bf[4];

#define DSREAD(s) do {                                                          \
        _Pragma("unroll")                                                       \
        for (int _i = 0; _i < 4; ++_i)                                          \
            af[_i] = *(const f16x8*)(As[s] + (wr * 64 + _i * 16 + l16) * 32 + xc * 8); \
        _Pragma("unroll")                                                       \
        for (int _j = 0; _j < 4; ++_j)                                          \
            bf[_j] = *(const f16x8*)(Bs[s] + (wc * 64 + _j * 16 + l16) * 32 + xc * 8); \
    } while (0)

#define DOMFMA() do {                                                           \
        _Pragma("unroll")                                                       \
        for (int _i = 0; _i < 4; ++_i)                                          \
            _Pragma("unroll")                                                   \
            for (int _j = 0; _j < 4; ++_j)                                      \
                acc[_i][_j] = __builtin_amdgcn_mfma_f32_16x16x32_f16(           \
                    af[_i], bf[_j], acc[_i][_j], 0, 0, 0);                      \
    } while (0)

    // ---- K-pipeline, run twice (diagnostic). acc ends at 2x true value.
#pragma unroll 1
    for (int rep = 0; rep < 2; ++rep) {
        __syncthreads();   // guard LDS slot reuse across reps

        // prologue: fill the pipeline 3 tiles deep, wait for tile 0 only
        STAGE(0, 0);
        STAGE(1, 1);
        STAGE(2, 2);
        asm volatile("s_waitcnt vmcnt(8)" ::: "memory");   // tile 0 landed
        __builtin_amdgcn_s_barrier();

#pragma unroll 1
        for (int kt = 0; kt < 13; ++kt) {
            const int s = kt % 3;
            DSREAD(s);
            asm volatile("s_waitcnt lgkmcnt(0)" ::: "memory");
            __builtin_amdgcn_s_barrier();
            STAGE(kt + 3, s);
            DOMFMA();
            asm volatile("s_waitcnt vmcnt(8)" ::: "memory");
            __builtin_amdgcn_s_barrier();
        }

        // tail: tiles 13,14,15 — no more staging; drain counted
        DSREAD(1);                                          // tile 13
        DOMFMA();
        asm volatile("s_waitcnt vmcnt(4)" ::: "memory");    // tile 14 landed
        __builtin_amdgcn_s_barrier();

        DSREAD(2);                                          // tile 14
        DOMFMA();
        asm volatile("s_waitcnt vmcnt(0)" ::: "memory");    // tile 15 landed
        __builtin_amdgcn_s_barrier();

        DSREAD(0);                                          // tile 15
        DOMFMA();
    }

#undef STAGE
#undef DSREAD
#undef DOMFMA

    // ---- epilogue 1: normal orientation, NON-TEMPORAL stores.
    // acc holds 2x the sum -> scale by exactly 0.5f.
    if (bi == bj) {
#pragma unroll
        for (int i = 0; i < 4; ++i) {
            const int grb = rowBase + wr * 64 + i * 16 + quad * 4;
#pragma unroll
            for (int j = 0; j < 4; ++j) {
                const int gc = colBase + wc * 64 + j * 16 + l16;
#pragma unroll
                for (int r = 0; r < 4; ++r) {
                    const int gr = grb + r;
                    float v = acc[i][j][r] * 0.5f + cb;
                    if (gr == gc) v = dvec[gr];
                    __builtin_nontemporal_store(v, C + (size_t)gr * NROWS + gc);
                }
            }
        }
    } else {
#pragma unroll
        for (int i = 0; i < 4; ++i) {
            const int grb = rowBase + wr * 64 + i * 16 + quad * 4;
#pragma unroll
            for (int j = 0; j < 4; ++j) {
                const int gc = colBase + wc * 64 + j * 16 + l16;
#pragma unroll
                for (int r = 0; r < 4; ++r)
                    __builtin_nontemporal_store(acc[i][j][r] * 0.5f + cb,
                                                C + (size_t)(grb + r) * NROWS + gc);
            }
        }

        // ---- epilogue 2: transposed orientation, f32x4 non-temporal.
#pragma unroll
        for (int j = 0; j < 4; ++j) {
            const int trow = colBase + wc * 64 + j * 16 + l16;   // row in C
#pragma unroll
            for (int i = 0; i < 4; ++i) {
                const int tcol = rowBase + wr * 64 + i * 16 + quad * 4;
                f32x4 v;
                v[0] = acc[i][j][0] * 0.5f + cb;
                v[1] = acc[i][j][1] * 0.5f + cb;
                v[2] = acc[i][j][2] * 0.5f + cb;
                v[3] = acc[i][j][3] * 0.5f + cb;
                __builtin_nontemporal_store(v, (f32x4*)(C + (size_t)trow * NROWS + tcol));
            }
        }
    }
}

// ---------------------------------------------------------------------------
extern "C" void kernel_launch(void* const* d_in, const int* in_sizes, int n_in,
                              void* d_out, int out_size, void* d_ws, size_t ws_size,
                              hipStream_t stream)
{
    const float* x     = (const float*)d_in[0];
    const float* muk   = (const float*)d_in[1];
    const float* rho   = (const float*)d_in[2];
    const float* vark  = (const float*)d_in[3];
    const float* mu_b  = (const float*)d_in[4];
    const float* var_b = (const float*)d_in[5];
    const float* cov_b = (const float*)d_in[6];

    float* out = (float*)d_out;                  // [0,8192): mu ; then cov row-major

    _Float16* xh = (_Float16*)d_ws;              // 8 MB
    _Float16* ah = xh + (size_t)NROWS * DDIM;    // 8 MB
    float* dvec  = (float*)(ah + (size_t)NROWS * DDIM);  // 32 KB

    prep_kernel<<<NROWS / 4, 256, 0, stream>>>(x, muk, rho, vark, mu_b, var_b,
                                               out, xh, ah, dvec);

    const int nblk = (NROWS / 128) * (NROWS / 128 + 1) / 2;   // 64*65/2 = 2080
    cov_kernel<<<nblk, 256, 0, stream>>>(ah, xh, dvec, cov_b, out + NROWS);
}

// Round 7
// 319.379 us; speedup vs baseline: 1.1606x; 1.1606x over previous
//
#include <hip/hip_runtime.h>
#include <math.h>

#define AS1 __attribute__((address_space(1)))
#define AS3 __attribute__((address_space(3)))

typedef _Float16 f16x8 __attribute__((ext_vector_type(8)));
typedef float f32x4 __attribute__((ext_vector_type(4)));

#define NROWS 8192
#define DDIM  512

// ---------------------------------------------------------------------------
// Kernel 1: per-row prep. One wave (64 lanes) per row; each lane owns 8 cols.
// ---------------------------------------------------------------------------
__global__ __launch_bounds__(256) void prep_kernel(
    const float* __restrict__ x,
    const float* __restrict__ muk,
    const float* __restrict__ rho,
    const float* __restrict__ vark,
    const float* __restrict__ mu_bias,
    const float* __restrict__ var_bias,
    float* __restrict__ mu_out,
    _Float16* __restrict__ xh,
    _Float16* __restrict__ ah,
    float* __restrict__ dvec)
{
    const int wave = threadIdx.x >> 6;
    const int lane = threadIdx.x & 63;
    const int row  = blockIdx.x * 4 + wave;
    const int k    = lane * 8;

    const float4 x0 = *(const float4*)(x + (size_t)row * DDIM + k);
    const float4 x1 = *(const float4*)(x + (size_t)row * DDIM + k + 4);
    const float4 m0 = *(const float4*)(muk + k);
    const float4 m1 = *(const float4*)(muk + k + 4);
    const float4 r0 = *(const float4*)(rho + k);
    const float4 r1 = *(const float4*)(rho + k + 4);
    const float4 v0 = *(const float4*)(vark + k);
    const float4 v1 = *(const float4*)(vark + k + 4);

    float xv[8] = {x0.x, x0.y, x0.z, x0.w, x1.x, x1.y, x1.z, x1.w};
    float rv[8] = {r0.x, r0.y, r0.z, r0.w, r1.x, r1.y, r1.z, r1.w};
    float mv[8] = {m0.x, m0.y, m0.z, m0.w, m1.x, m1.y, m1.z, m1.w};
    float vv[8] = {v0.x, v0.y, v0.z, v0.w, v1.x, v1.y, v1.z, v1.w};

    f16x8 hx, ha;
    float dm = 0.f, dv = 0.f;
#pragma unroll
    for (int j = 0; j < 8; ++j) {
        hx[j] = (_Float16)xv[j];
        ha[j] = (_Float16)(xv[j] * rv[j]);
        dm += xv[j] * mv[j];
        dv += xv[j] * vv[j];
    }
    *(f16x8*)(xh + (size_t)row * DDIM + k) = hx;
    *(f16x8*)(ah + (size_t)row * DDIM + k) = ha;

#pragma unroll
    for (int off = 32; off > 0; off >>= 1) {
        dm += __shfl_down(dm, off, 64);
        dv += __shfl_down(dv, off, 64);
    }
    if (lane == 0) {
        mu_out[row] = dm + mu_bias[0];
        float z  = dv + var_bias[0];
        float sp = fmaxf(z, 0.f) + log1pf(expf(-fabsf(z)));  // stable softplus
        dvec[row] = sp + 1e-8f;
    }
}

// ---------------------------------------------------------------------------
// Kernel 2: C[i,j] = sum_k ah[i,k]*xh[j,k] + cov_bias ; C[i,i] = dvec[i].
//
// v7: FULL-LINE STORE EPILOGUE. Round-6 diagnostic: K-loop = ~38us; the old
// epilogue = ~90-115us at a fixed ~5e10 HBM-transactions/s ceiling with 64-B
// write granules (half-line). Fix: bulk LDS transpose (2 passes/orientation,
// 64x132-f32 half-tile = 33 KB reusing the 48 KB staging LDS); read-out is
// lane-contiguous ds_read_b128 + NT f32x4 stores where 32 consecutive lanes
// cover 512 B = 4 full 128-B lines. Conflict analysis @ stride 132:
//   normal write  (b32, fixed i,j,r): banks = l16 + 16*quad -> 2-way (free)
//   transp write  (b128 of acc[i][j], r contiguous cols): uniform over the
//                 8 16-B slot groups -> conflict-free
//   read-out      (b128, consecutive lanes consecutive addrs) -> conflict-free
// K-loop unchanged (counted-vmcnt depth-2, cell-major order, read swizzle).
// ---------------------------------------------------------------------------
__device__ __forceinline__ void gload_lds16(const void* g, void* l)
{
    __builtin_amdgcn_global_load_lds((AS1 void*)g, (AS3 void*)l, 16, 0, 0);
}

__global__ __launch_bounds__(256) void cov_kernel(
    const _Float16* __restrict__ A,   // ah: 8192 x 512 (rows of x*rho)
    const _Float16* __restrict__ B,   // xh: 8192 x 512 (rows of x)
    const float* __restrict__ dvec,
    const float* __restrict__ cov_bias,
    float* __restrict__ C)
{
    // 48 KB shared, aliased: staging (3x8KB A + 3x8KB B) then epilogue f32.
    __shared__ __align__(16) char smem[49152];
    _Float16* As0 = (_Float16*)smem;            // 3 slots x 4096 halves
    _Float16* Bs0 = (_Float16*)(smem + 24576);  // 3 slots x 4096 halves
    float*    ep  = (float*)smem;               // 64 x 132 f32 = 33792 B

    const int t    = threadIdx.x;
    const int lane = t & 63;
    const int wave = t >> 6;
    const int wr   = wave >> 1;         // 0..1 : 64-row half
    const int wc   = wave & 1;          // 0..1 : 64-col half
    const int quad = lane >> 4;         // 0..3
    const int l16  = lane & 15;
    const int xc   = quad ^ ((l16 >> 1) & 3);   // swizzled read chunk

    // XCD-aware chunked swizzle over cell-major order.
    const int bid = blockIdx.x;
    const int tt  = (bid & 7) * 260 + (bid >> 3);

    // cell-major decode: cells are 8x8 blocks; blocks before cell-row SI:
    // base(SI) = 32*SI^2 + 4*SI
    int SI = (int)((sqrtf(1.f + 8.f * (float)tt) - 1.f) * 0.0625f);
    while (32 * (SI + 1) * (SI + 1) + 4 * (SI + 1) <= tt) ++SI;
    while (32 * SI * SI + 4 * SI > tt) --SI;
    const int rem = tt - (32 * SI * SI + 4 * SI);
    int SJ, ii, jj;
    if (rem < 64 * SI) {                 // full off-diagonal cell
        SJ = rem >> 6;
        const int w = rem & 63;
        ii = w >> 3;
        jj = w & 7;
    } else {                             // diagonal cell: 36 blocks, jj<=ii
        const int w = rem - 64 * SI;
        SJ = SI;
        ii = (int)((sqrtf(8.f * (float)w + 1.f) - 1.f) * 0.5f);
        while ((ii + 1) * (ii + 2) / 2 <= w) ++ii;
        while (ii * (ii + 1) / 2 > w) --ii;
        jj = w - ii * (ii + 1) / 2;
    }
    const int bi = SI * 8 + ii;
    const int bj = SJ * 8 + jj;

    const int rowBase = bi * 128;
    const int colBase = bj * 128;
    const float cb = cov_bias[0];

    f32x4 acc[4][4] = {};

    // staging: thread t owns LDS slot (row r = t>>2, chunk c = t&3, 16 B).
    // Pre-swizzled global source chunk g = c ^ ((r>>1)&3)  (rule 21).
    const int sr = t >> 2;
    const int sg = (t & 3) ^ ((sr >> 1) & 3);
    const _Float16* ga = A + ((size_t)(rowBase + sr)) * DDIM + sg * 8;
    const _Float16* gb = B + ((size_t)(colBase + sr)) * DDIM + sg * 8;

#define STAGE(kt, s) do {                                                \
        const int _k0 = (kt) * 32;                                       \
        gload_lds16(ga + _k0,             As0 + (s) * 4096 + t * 8);     \
        gload_lds16(ga + 64 * DDIM + _k0, As0 + (s) * 4096 + 2048 + t * 8); \
        gload_lds16(gb + _k0,             Bs0 + (s) * 4096 + t * 8);     \
        gload_lds16(gb + 64 * DDIM + _k0, Bs0 + (s) * 4096 + 2048 + t * 8); \
    } while (0)

    f16x8 af[4], bf[4];

#define DSREAD(s) do {                                                          \
        _Pragma("unroll")                                                       \
        for (int _i = 0; _i < 4; ++_i)                                          \
            af[_i] = *(const f16x8*)(As0 + (s) * 4096 + (wr * 64 + _i * 16 + l16) * 32 + xc * 8); \
        _Pragma("unroll")                                                       \
        for (int _j = 0; _j < 4; ++_j)                                          \
            bf[_j] = *(const f16x8*)(Bs0 + (s) * 4096 + (wc * 64 + _j * 16 + l16) * 32 + xc * 8); \
    } while (0)

#define DOMFMA() do {                                                           \
        _Pragma("unroll")                                                       \
        for (int _i = 0; _i < 4; ++_i)                                          \
            _Pragma("unroll")                                                   \
            for (int _j = 0; _j < 4; ++_j)                                      \
                acc[_i][_j] = __builtin_amdgcn_mfma_f32_16x16x32_f16(           \
                    af[_i], bf[_j], acc[_i][_j], 0, 0, 0);                      \
    } while (0)

    // prologue: fill the pipeline 3 tiles deep, wait for tile 0 only
    STAGE(0, 0);
    STAGE(1, 1);
    STAGE(2, 2);
    asm volatile("s_waitcnt vmcnt(8)" ::: "memory");   // tile 0 landed
    __builtin_amdgcn_s_barrier();

#pragma unroll 1
    for (int kt = 0; kt < 13; ++kt) {
        const int s = kt % 3;
        DSREAD(s);
        asm volatile("s_waitcnt lgkmcnt(0)" ::: "memory");
        __builtin_amdgcn_s_barrier();
        STAGE(kt + 3, s);
        DOMFMA();
        asm volatile("s_waitcnt vmcnt(8)" ::: "memory");
        __builtin_amdgcn_s_barrier();
    }

    // tail: tiles 13,14,15 — no more staging; drain counted
    DSREAD(1);                                          // tile 13
    DOMFMA();
    asm volatile("s_waitcnt vmcnt(4)" ::: "memory");    // tile 14 landed
    __builtin_amdgcn_s_barrier();

    DSREAD(2);                                          // tile 14
    DOMFMA();
    asm volatile("s_waitcnt vmcnt(0)" ::: "memory");    // tile 15 landed
    __builtin_amdgcn_s_barrier();

    DSREAD(0);                                          // tile 15
    DOMFMA();

#undef STAGE
#undef DSREAD
#undef DOMFMA

    // =======================================================================
    // Epilogue: bulk LDS transpose -> full-128B-line NT stores.
    // acc[i][j][r] is C value at (rowBase + wr*64 + i*16 + quad*4 + r,
    //                             colBase + wc*64 + j*16 + l16).
    // =======================================================================

    // ---- normal orientation: 2 passes over row-halves h (wr == h active)
#pragma unroll 1
    for (int h = 0; h < 2; ++h) {
        __syncthreads();   // LDS free (staging done / previous pass read)
        if (wr == h) {
#pragma unroll
            for (int i = 0; i < 4; ++i)
#pragma unroll
                for (int j = 0; j < 4; ++j)
#pragma unroll
                    for (int r = 0; r < 4; ++r)
                        ep[(i * 16 + quad * 4 + r) * 132 + wc * 64 + j * 16 + l16]
                            = acc[i][j][r] + cb;
        }
        __syncthreads();
        // read-out: 32 lanes cover one 512-B row chunk (4 full lines)
#pragma unroll
        for (int n = 0; n < 8; ++n) {
            const int idx = n * 256 + t;
            const int lr  = idx >> 5;
            const int c4  = idx & 31;
            f32x4 v = *(const f32x4*)(ep + lr * 132 + c4 * 4);
            const int gr = rowBase + h * 64 + lr;
            const int gc = colBase + c4 * 4;
            if (bi == bj) {
                const int d = gr - gc;
                if (0 <= d && d < 4) v[d] = dvec[gr];
            }
            __builtin_nontemporal_store(v, (f32x4*)(C + (size_t)gr * NROWS + gc));
        }
    }

    // ---- transposed orientation (off-diagonal blocks): T[gc][gr] = value.
    // T-halves by wc == h2; write is ds_write_b128 (r = contiguous T-cols).
    if (bi != bj) {
#pragma unroll 1
        for (int h2 = 0; h2 < 2; ++h2) {
            __syncthreads();
            if (wc == h2) {
#pragma unroll
                for (int i = 0; i < 4; ++i)
#pragma unroll
                    for (int j = 0; j < 4; ++j) {
                        f32x4 v;
                        v[0] = acc[i][j][0] + cb;
                        v[1] = acc[i][j][1] + cb;
                        v[2] = acc[i][j][2] + cb;
                        v[3] = acc[i][j][3] + cb;
                        *(f32x4*)(ep + (j * 16 + l16) * 132
                                     + wr * 64 + i * 16 + quad * 4) = v;
                    }
            }
            __syncthreads();
#pragma unroll
            for (int n = 0; n < 8; ++n) {
                const int idx = n * 256 + t;
                const int lr  = idx >> 5;
                const int c4  = idx & 31;
                f32x4 v = *(const f32x4*)(ep + lr * 132 + c4 * 4);
                const int gr = colBase + h2 * 64 + lr;   // row in C (T-row)
                const int gc = rowBase + c4 * 4;         // col in C (T-col)
                __builtin_nontemporal_store(v, (f32x4*)(C + (size_t)gr * NROWS + gc));
            }
        }
    }
}

// ---------------------------------------------------------------------------
extern "C" void kernel_launch(void* const* d_in, const int* in_sizes, int n_in,
                              void* d_out, int out_size, void* d_ws, size_t ws_size,
                              hipStream_t stream)
{
    const float* x     = (const float*)d_in[0];
    const float* muk   = (const float*)d_in[1];
    const float* rho   = (const float*)d_in[2];
    const float* vark  = (const float*)d_in[3];
    const float* mu_b  = (const float*)d_in[4];
    const float* var_b = (const float*)d_in[5];
    const float* cov_b = (const float*)d_in[6];

    float* out = (float*)d_out;                  // [0,8192): mu ; then cov row-major

    _Float16* xh = (_Float16*)d_ws;              // 8 MB
    _Float16* ah = xh + (size_t)NROWS * DDIM;    // 8 MB
    float* dvec  = (float*)(ah + (size_t)NROWS * DDIM);  // 32 KB

    prep_kernel<<<NROWS / 4, 256, 0, stream>>>(x, muk, rho, vark, mu_b, var_b,
                                               out, xh, ah, dvec);

    const int nblk = (NROWS / 128) * (NROWS / 128 + 1) / 2;   // 64*65/2 = 2080
    cov_kernel<<<nblk, 256, 0, stream>>>(ah, xh, dvec, cov_b, out + NROWS);
}